// Round 2
// baseline (171826.892 us; speedup 1.0000x reference)
//
#include <hip/hip_runtime.h>
#include <stdint.h>

typedef unsigned short ushortT;
typedef unsigned long long u64T;
typedef __attribute__((ext_vector_type(8))) short short8;
typedef __attribute__((ext_vector_type(4))) float f32x4;

#define B_ 128
#define T_ 512
#define I_ 512
#define H_ 512
#define NG 1536     // 3*512 gate cols
#define NTOT 1544   // + 8 q cols

__device__ __forceinline__ float bf2f(ushortT u){
  union { unsigned int i; float f; } v; v.i = ((unsigned int)u) << 16; return v.f;
}
__device__ __forceinline__ ushortT f2bf(float f){           // RNE
  union { float f; unsigned int i; } v; v.f = f;
  unsigned int u = v.i;
  u += 0x7fffu + ((u >> 16) & 1u);
  return (ushortT)(u >> 16);
}
// truncating split: x == hi + lo to ~17 mantissa bits
__device__ __forceinline__ void splitf(float x, ushortT& hi, ushortT& lo){
  union { float f; unsigned int i; } v; v.f = x;
  hi = (ushortT)(v.i >> 16);
  union { unsigned int i; float f; } h; h.i = v.i & 0xffff0000u;
  union { float f; unsigned int i; } r; r.f = x - h.f;
  lo = (ushortT)(r.i >> 16);
}
__device__ __forceinline__ unsigned int packsplit(float x){
  ushortT hi, lo; splitf(x, hi, lo);
  return ((unsigned int)lo << 16) | (unsigned int)hi;
}
__device__ __forceinline__ float sigf(float x){ return 1.f / (1.f + __expf(-x)); }
__device__ __forceinline__ float tanhfast(float x){
  float e = __expf(-2.f * fabsf(x));
  float t = (1.f - e) / (1.f + e);
  return copysignf(t, x);
}
__device__ __forceinline__ void stx(float* p, size_t i, float v){ p[i] = v; }
__device__ __forceinline__ void stx(ushortT* p, size_t i, float v){ p[i] = f2bf(v); }
__device__ __forceinline__ float ldx(const float* p, size_t i){ return p[i]; }
__device__ __forceinline__ float ldx(const ushortT* p, size_t i){ return bf2f(p[i]); }
__device__ __forceinline__ unsigned int get_xcc(){
  unsigned int r;
  asm("s_getreg_b32 %0, hwreg(HW_REG_XCC_ID)" : "=s"(r));
  return r;
}
// L1-bypassing (sc0) load: resolves at the per-XCD L2 — the poll primitive
// for same-XCD flags written by plain stores.
__device__ __forceinline__ unsigned int ld_u32_sc0(const unsigned int* p){
  unsigned int v;
  asm volatile("global_load_dword %0, %1, off sc0\n\ts_waitcnt vmcnt(0)"
               : "=v"(v) : "v"(p) : "memory");
  return v;
}

// ---------------------------------------------------------------------------
// Kernel A (validated r3/r4): weight prep. UNCHANGED.
// ---------------------------------------------------------------------------
__global__ __launch_bounds__(256) void prep_w(
    const float* __restrict__ Wi, const float* __restrict__ Wg,
    const float* __restrict__ Wo, const float* __restrict__ Wf,
    ushortT* __restrict__ btx, ushortT* __restrict__ bth_hi,
    ushortT* __restrict__ bth_lo, int wlo)
{
  int e = blockIdx.x * 256 + threadIdx.x;   // 1544*512 = 3088*256
  int n = e >> 9;
  int k = e & 511;
  const float* W; int ld, c;
  if (n < 512){ W = Wi; ld = 512; c = n; }
  else if (n < 1024){ W = Wg; ld = 512; c = n - 512; }
  else if (n < 1536){ W = Wo; ld = 512; c = n - 1024; }
  else { W = Wf; ld = 8; c = n - 1536; }
  btx[e] = f2bf(W[(size_t)k * ld + c]);
  float wh = W[(size_t)(512 + k) * ld + c];
  ushortT hi, lo; splitf(wh, hi, lo);
  bth_hi[e] = hi;
  if (wlo) bth_lo[e] = lo;
}

// ---------------------------------------------------------------------------
// Kernel B (validated r3/r4): xproj. UNCHANGED.
// ---------------------------------------------------------------------------
template<typename XPT, bool QX32, int XPST>
__global__ __launch_bounds__(256) void xproj_gemm(
    const float* __restrict__ x, const ushortT* __restrict__ btx,
    const float* __restrict__ bi, const float* __restrict__ bg,
    const float* __restrict__ bo, const float* __restrict__ bfv,
    XPT* __restrict__ xp, float* __restrict__ qx)
{
  __shared__ ushortT As[128][72];   // +8 pad
  __shared__ ushortT Bs[128][72];
  const int tid = threadIdx.x;
  const int n0 = blockIdx.x * 128;
  const int m0 = blockIdx.y * 128;
  const int wid = tid >> 6, lane = tid & 63;
  const int nn = lane & 15, quad = lane >> 4;

  f32x4 acc[2][8];
  #pragma unroll
  for (int a = 0; a < 2; ++a)
    #pragma unroll
    for (int b = 0; b < 8; ++b) acc[a][b] = (f32x4){0.f,0.f,0.f,0.f};

  for (int kb = 0; kb < 8; ++kb){
    #pragma unroll
    for (int u = 0; u < 4; ++u){
      int idx = u*256 + tid;
      int r = idx >> 3, k8 = (idx & 7) * 8;
      const float* xa = &x[(size_t)(m0 + r) * I_ + kb*64 + k8];
      f32x4 f0 = *(const f32x4*)xa;
      f32x4 f1 = *(const f32x4*)(xa + 4);
      short8 av;
      #pragma unroll
      for (int i = 0; i < 4; ++i){ av[i] = (short)f2bf(f0[i]); av[4+i] = (short)f2bf(f1[i]); }
      *(short8*)&As[r][k8] = av;
      int ng = n0 + r;
      short8 bv = {0,0,0,0,0,0,0,0};
      if (ng < NTOT)
        bv = *(const short8*)&btx[(size_t)ng * 512 + kb*64 + k8];
      *(short8*)&Bs[r][k8] = bv;
    }
    __syncthreads();
    #pragma unroll
    for (int kc = 0; kc < 2; ++kc){
      int ko = kc*32 + quad*8;
      short8 a0 = *(const short8*)&As[wid*32 + nn][ko];
      short8 a1 = *(const short8*)&As[wid*32 + 16 + nn][ko];
      #pragma unroll
      for (int nt = 0; nt < 8; ++nt){
        short8 b = *(const short8*)&Bs[nt*16 + nn][ko];
        acc[0][nt] = __builtin_amdgcn_mfma_f32_16x16x32_bf16(a0, b, acc[0][nt], 0,0,0);
        acc[1][nt] = __builtin_amdgcn_mfma_f32_16x16x32_bf16(a1, b, acc[1][nt], 0,0,0);
      }
    }
    __syncthreads();
  }
  #pragma unroll
  for (int nt = 0; nt < 8; ++nt){
    int c = n0 + nt*16 + nn;
    if (c >= NTOT) continue;
    float bias;
    if (c < 512) bias = bi[c];
    else if (c < 1024) bias = bg[c - 512];
    else if (c < NG) bias = bo[c - 1024];
    else bias = bfv[c - NG];
    #pragma unroll
    for (int mt = 0; mt < 2; ++mt){
      int rb = m0 + wid*32 + mt*16 + quad*4;
      #pragma unroll
      for (int r = 0; r < 4; ++r){
        float v = acc[mt][nt][r] + bias;
        if (c < NG)
          stx(xp, (size_t)(rb + r) * XPST + c, v);
        else if (QX32)
          qx[(size_t)(rb + r) * 8 + (c - NG)] = v;
        else
          stx(xp, (size_t)(rb + r) * XPST + c, v);
      }
    }
  }
}

// ---------------------------------------------------------------------------
// Kernel C: persistent recurrence. r6 — PAIRED-GROUP PIPELINE.
//
// PMC r5: MfmaUtil 6.3%, VALUBusy 12.8% => ~80% of the 5.17us step is still
// waiting (max-of-32 flag coupling through MALL-latency detection + zero
// slack, x512 steps). The 8 batch groups are INDEPENDENT recurrences, so:
//
//  * 128 active blocks (even blk&7 -> XCDs 0/2/4/6; r1-proven mapping, with
//    the same handshake + agent-scope fallback). Block (p,s) owns col-slice
//    s for BOTH groups 2p and 2p+1 — the 116KB LDS weight block depends only
//    on the col-slice, so it is shared; sH is time-shared between phases.
//  * Per step: pollA/loadA/mfmaA/updateA/flagA, then the same for B. In
//    steady state peers posted B's flag one half-phase ago -> polls hit on
//    the first read; each group-phase gives the other a half-step of slack
//    that absorbs straggler jitter.
//  * Flags now also L2-resident in same-XCD mode: plain store (ordered
//    behind h stores by the vmcnt-draining __syncthreads, same L2 resolve
//    point) + sc0 L1-bypass poll loads. MALL is out of the loop entirely.
//  * All 4 waves poll (wave-local ballot) -> no barrier between poll and
//    sH load. 3 barriers per group-phase.
//  * xp addends prefetched one step ahead (registers), so the sc0 poll's
//    vmcnt(0) never serializes HBM latency into the critical path.
//  * h exchanged as packed (lo16<<16)|hi16 split (r5-validated); dout
//    rewritten with f32 two steps later; final two slices fixed after an
//    all-flags>=T poll. Dual MFMA accumulators (r5).
// ---------------------------------------------------------------------------
template<typename XPT, bool QX32, bool WLO, int XPST>
__global__ __launch_bounds__(256) void qlstm_rec(
    float* __restrict__ dout, const float* __restrict__ h0,
    const float* __restrict__ c0,
    const ushortT* __restrict__ bth_hi, const ushortT* __restrict__ bth_lo,
    const XPT* __restrict__ xp, const float* __restrict__ qx,
    const float* __restrict__ Wfp, const float* __restrict__ bfp,
    const float* __restrict__ qa, const float* __restrict__ qbv,
    const float* __restrict__ qpar, unsigned int* __restrict__ cnt)
{
  __shared__ ushortT sWt[WLO ? 2 : 1][56][520];
  __shared__ unsigned int sH[16][516];   // packed (lo<<16)|hi per element
  __shared__ float sGb[3][16][16];
  __shared__ float sQbuf[16][8];
  __shared__ float sWfp[8][16];
  __shared__ float sBfp[16];
  __shared__ float sQa[3], sQn[3], sQp[8];
  __shared__ int sMode;

  const int xk = blockIdx.x & 7;
  if (xk & 1) return;                    // 128 idle blocks exit (XCDs 1,3,5,7)
  const int tid = threadIdx.x;
  const int p = xk >> 1;                 // pair 0..3 -> groups 2p, 2p+1
  const int s = blockIdx.x >> 3;         // col slice 0..31
  const int j0 = s * 16;
  const int wid = tid >> 6, lane = tid & 63;
  const int nn = lane & 15, quad = lane >> 4;

  unsigned int* flg0 = cnt + ((p*2    ) << 5);   // flags[group][slice]
  unsigned int* flg1 = cnt + ((p*2 + 1) << 5);
  unsigned int* xpub = cnt + 1024;               // byte offset 4096

  // publish XCC id early so the handshake poll below rarely waits
  if (tid == 0)
    __hip_atomic_store(&xpub[blockIdx.x], (get_xcc() & 0xffu) | 0x100u,
                       __ATOMIC_RELAXED, __HIP_MEMORY_SCOPE_AGENT);

  // one-time LDS weight staging (rows: 16 Wi | 16 Wg | 16 Wo | 8 Wf)
  for (int u = tid; u < 56*64; u += 256){
    int r = u >> 6, c8 = (u & 63) * 8;
    int src = (r < 48) ? ((r >> 4) * 512 + j0 + (r & 15)) : (NG + (r - 48));
    *(short8*)&sWt[0][r][c8] = *(const short8*)&bth_hi[(size_t)src * 512 + c8];
    if (WLO)
      *(short8*)&sWt[WLO?1:0][r][c8] = *(const short8*)&bth_lo[(size_t)src * 512 + c8];
  }
  if (tid < 128){ int nq = tid >> 4, jj = tid & 15; sWfp[nq][jj] = Wfp[nq*512 + j0 + jj]; }
  if (tid < 16) sBfp[tid] = bfp[j0 + tid];
  if (tid < 3){ sQa[tid] = qa[tid]; sQn[tid] = qbv[tid]; }
  if (tid < 8) sQp[tid] = qpar[tid];

  // handshake: do all 32 blocks of this pair (blk = 2p + 8*s') share an XCD?
  if (wid == 0){
    int sl = lane & 31;
    unsigned int v = 0; long it = 0; bool timeout = false;
    for (;;){
      v = __hip_atomic_load(&xpub[(p << 1) + (sl << 3)], __ATOMIC_RELAXED,
                            __HIP_MEMORY_SCOPE_AGENT);
      if (__ballot(v != 0u) == ~0ull) break;
      __builtin_amdgcn_s_sleep(8);
      if (++it > 2000000L){ timeout = true; break; }
    }
    unsigned int v0 = __shfl(v, 0);
    bool same = (__ballot(v == v0) == ~0ull);
    if (tid == 0) sMode = (!timeout && same) ? 1 : 0;
  }

  const int eb = tid >> 4, ej = tid & 15;
  const int jg = j0 + ej;
  float cst[2];
  #pragma unroll
  for (int gi = 0; gi < 2; ++gi)
    cst[gi] = c0[(size_t)((p*2 + gi)*16 + eb) * H_ + jg];

  const int wrow = (wid < 3) ? (wid*16 + nn) : (48 + (nn & 7));
  const int ncol = (wid < 3) ? (wid*512 + j0 + nn) : (NG + nn);
  const bool colok = (wid < 3) || (nn < 8);

  // cooperative h-loader mapping: row = tid>>4, lane-interleaved columns
  const int lr = tid >> 4;
  const int lc0 = (tid & 15) * 2;          // u64 loads (agent path, t=0)
  const int lc4 = (tid & 15) * 4;          // uint4 loads (L2 path)
  const int lxs = (lr & 7) << 3;           // XOR swizzle (8-elem chunks)
  const int rxs = (nn & 7) << 3;
  bool dead = false;
  float hp1[2] = {0.f, 0.f}, hp2[2] = {0.f, 0.f};   // f32 h delay lines
  float xpc[2][4], xpn[2][4];
  unsigned int* doutU = (unsigned int*)dout;

  // prologue: xp addends for t=0
  #pragma unroll
  for (int gj = 0; gj < 2; ++gj){
    const int bq = (p*2 + gj) * 16;
    #pragma unroll
    for (int r = 0; r < 4; ++r){
      int b = quad*4 + r;
      if (!colok){ xpc[gj][r] = 0.f; continue; }
      if ((wid < 3) || !QX32)
        xpc[gj][r] = ldx(xp, ((size_t)(bq + b) * T_ + 0) * XPST + ncol);
      else
        xpc[gj][r] = qx[((size_t)(bq + b) * T_ + 0) * 8 + nn];
    }
  }

  __syncthreads();                         // staging + sMode ready
  const bool l2m = (sMode != 0);

  for (int t = 0; t < T_; ++t){
    #pragma unroll
    for (int gi = 0; gi < 2; ++gi){
      const int b0 = (p*2 + gi) * 16;
      unsigned int* flg = gi ? flg1 : flg0;

      if (t > 0){
        // all-wave poll: flg[0..31] >= t (each flag checked by 2 lanes)
        {
          const unsigned int* fp = &flg[lane & 31];
          bool ok = false; long it = 0;
          for (;;){
            if (!ok){
              unsigned int v;
              if (l2m) v = ld_u32_sc0(fp);
              else     v = __hip_atomic_load(fp, __ATOMIC_RELAXED,
                                             __HIP_MEMORY_SCOPE_AGENT);
              ok = (v >= (unsigned int)t);
            }
            if (__ballot(ok) == ~0ull) break;
            __builtin_amdgcn_s_sleep(1);
            if (++it > 20000000L){ dead = true; break; }
          }
        }
        const unsigned int* srow = doutU + ((size_t)(b0 + lr) * T_ + (t - 1)) * H_;
        if (l2m){
          // same-XCD: plain loads resolved in the shared L2 (t-unique addrs)
          #pragma unroll
          for (int i = 0; i < 8; ++i){
            int c = lc4 + i*64;
            *(uint4*)&sH[lr][c ^ lxs] = *(const uint4*)(srow + c);
          }
        } else {
          #pragma unroll
          for (int i = 0; i < 16; ++i){
            int c = lc0 + i*32;
            u64T v = __hip_atomic_load((const u64T*)(srow + c),
                                       __ATOMIC_RELAXED, __HIP_MEMORY_SCOPE_AGENT);
            *(u64T*)&sH[lr][c ^ lxs] = v;
          }
        }
        // flags>=t proves all peers consumed slice t-2 -> f32 rewrite safe
        if (t >= 2)
          dout[((size_t)(b0 + eb) * T_ + (t - 2)) * H_ + jg] = hp2[gi];
      } else {
        const float* srow = h0 + (size_t)(b0 + lr) * H_;
        #pragma unroll
        for (int i = 0; i < 16; ++i){
          int c = lc0 + i*32;
          u64T pk = (u64T)packsplit(srow[c]) | ((u64T)packsplit(srow[c + 1]) << 32);
          *(u64T*)&sH[lr][c ^ lxs] = pk;
        }
      }

      if (gi == 0){
        // prefetch next step's xp addends; consumed at t+1, drained (free)
        // at phase B's poll after ~2k cycles of compute.
        int tn = (t + 1 < T_) ? (t + 1) : t;
        #pragma unroll
        for (int gj = 0; gj < 2; ++gj){
          const int bq = (p*2 + gj) * 16;
          #pragma unroll
          for (int r = 0; r < 4; ++r){
            int b = quad*4 + r;
            if (!colok){ xpn[gj][r] = 0.f; continue; }
            if ((wid < 3) || !QX32)
              xpn[gj][r] = ldx(xp, ((size_t)(bq + b) * T_ + tn) * XPST + ncol);
            else
              xpn[gj][r] = qx[((size_t)(bq + b) * T_ + tn) * 8 + nn];
          }
        }
      }
      __syncthreads();

      f32x4 ac0 = {0.f,0.f,0.f,0.f}, ac1 = {0.f,0.f,0.f,0.f};
      #pragma unroll
      for (int kc = 0; kc < 16; ++kc){
        const unsigned int* hp = &sH[nn][(kc*32 + quad*8) ^ rxs];
        uint4 p0 = *(const uint4*)hp;
        uint4 p1 = *(const uint4*)(hp + 4);
        union { short8 sv; unsigned int u[4]; } Ah, Al;
        Ah.u[0] = __builtin_amdgcn_perm(p0.y, p0.x, 0x05040100u);
        Ah.u[1] = __builtin_amdgcn_perm(p0.w, p0.z, 0x05040100u);
        Ah.u[2] = __builtin_amdgcn_perm(p1.y, p1.x, 0x05040100u);
        Ah.u[3] = __builtin_amdgcn_perm(p1.w, p1.z, 0x05040100u);
        short8 bhi = *(const short8*)&sWt[0][wrow][kc*32 + quad*8];
        f32x4& acc = (kc & 1) ? ac1 : ac0;
        if (WLO){
          Al.u[0] = __builtin_amdgcn_perm(p0.y, p0.x, 0x07060302u);
          Al.u[1] = __builtin_amdgcn_perm(p0.w, p0.z, 0x07060302u);
          Al.u[2] = __builtin_amdgcn_perm(p1.y, p1.x, 0x07060302u);
          Al.u[3] = __builtin_amdgcn_perm(p1.w, p1.z, 0x07060302u);
          short8 blo = *(const short8*)&sWt[WLO?1:0][wrow][kc*32 + quad*8];
          acc = __builtin_amdgcn_mfma_f32_16x16x32_bf16(Al.sv, bhi, acc, 0,0,0);
          acc = __builtin_amdgcn_mfma_f32_16x16x32_bf16(Ah.sv, blo, acc, 0,0,0);
        }
        acc = __builtin_amdgcn_mfma_f32_16x16x32_bf16(Ah.sv, bhi, acc, 0,0,0);
      }
      f32x4 accv = ac0 + ac1;

      if (wid < 3){
        #pragma unroll
        for (int r = 0; r < 4; ++r){
          float v = accv[r] + xpc[gi][r];
          v = (wid == 1) ? tanhfast(v) : sigf(v);
          sGb[wid][quad*4 + r][nn] = v;
        }
      } else if (nn < 8){
        float a0 = sQa[0], a1 = sQa[1], a2 = sQa[2];
        float n0v = sQn[0], n1 = sQn[1], n2 = sQn[2];
        float qp = sQp[nn];
        #pragma unroll
        for (int r = 0; r < 4; ++r){
          float v = accv[r] + xpc[gi][r];
          v = tanhfast(v * a0 + n0v);
          v = tanhfast(v * a1 + n1);
          v = tanhfast(v * a2 + n2);
          sQbuf[quad*4 + r][nn] = v + qp;
        }
      }
      __syncthreads();

      float fpre = sBfp[ej];
      #pragma unroll
      for (int nq = 0; nq < 8; ++nq)
        fpre += sQbuf[eb][nq] * sWfp[nq][ej];
      float f = sigf(fpre);
      float iv = sGb[0][eb][ej], gv = sGb[1][eb][ej], ov = sGb[2][eb][ej];
      cst[gi] = f * cst[gi] + iv * gv;
      float hv = ov * tanhfast(cst[gi]);
      unsigned int pk = packsplit(hv);
      size_t oidx = ((size_t)(b0 + eb) * T_ + t) * H_ + jg;
      if (l2m)
        doutU[oidx] = pk;                           // plain store, L2-resolved
      else
        __hip_atomic_store(&doutU[oidx], pk, __ATOMIC_RELAXED,
                           __HIP_MEMORY_SCOPE_AGENT);
      hp2[gi] = hp1[gi]; hp1[gi] = hv;

      __syncthreads();   // s_waitcnt vmcnt(0) before s_barrier: h committed
      if (tid == 0 && !dead){
        if (l2m)
          __hip_atomic_store(&flg[s], (unsigned int)(t + 1), __ATOMIC_RELAXED,
                             __HIP_MEMORY_SCOPE_WORKGROUP);   // plain store -> L2
        else
          __hip_atomic_store(&flg[s], (unsigned int)(t + 1), __ATOMIC_RELAXED,
                             __HIP_MEMORY_SCOPE_AGENT);
      }
    }

    #pragma unroll
    for (int gj = 0; gj < 2; ++gj)
      #pragma unroll
      for (int r = 0; r < 4; ++r) xpc[gj][r] = xpn[gj][r];
  }

  // Final slice fixup: slice T-2 may still be read by stragglers at their
  // step T-1 -> wait for every flag of the group to reach T first.
  #pragma unroll
  for (int gi = 0; gi < 2; ++gi){
    unsigned int* flg = gi ? flg1 : flg0;
    if (wid == 0 && !dead){
      const unsigned int* fp = &flg[lane & 31];
      bool ok = false; long it = 0;
      for (;;){
        if (!ok){
          unsigned int v;
          if (l2m) v = ld_u32_sc0(fp);
          else     v = __hip_atomic_load(fp, __ATOMIC_RELAXED,
                                         __HIP_MEMORY_SCOPE_AGENT);
          ok = (v >= (unsigned int)T_);
        }
        if (__ballot(ok) == ~0ull) break;
        __builtin_amdgcn_s_sleep(1);
        if (++it > 20000000L) break;
      }
    }
    __syncthreads();
    const int b0 = (p*2 + gi) * 16;
    dout[((size_t)(b0 + eb) * T_ + (T_ - 2)) * H_ + jg] = hp2[gi];
    dout[((size_t)(b0 + eb) * T_ + (T_ - 1)) * H_ + jg] = hp1[gi];
  }
}

// ---------------------------------------------------------------------------
extern "C" void kernel_launch(void* const* d_in, const int* in_sizes, int n_in,
                              void* d_out, int out_size, void* d_ws, size_t ws_size,
                              hipStream_t stream)
{
  const float* x   = (const float*)d_in[0];
  const float* h0  = (const float*)d_in[1];
  const float* c0  = (const float*)d_in[2];
  const float* Wi  = (const float*)d_in[3];
  const float* bi  = (const float*)d_in[4];
  const float* Wg  = (const float*)d_in[5];
  const float* bg  = (const float*)d_in[6];
  const float* Wo  = (const float*)d_in[7];
  const float* bo  = (const float*)d_in[8];
  const float* Wf  = (const float*)d_in[9];
  const float* bfv = (const float*)d_in[10];
  const float* qa  = (const float*)d_in[11];
  const float* qb  = (const float*)d_in[12];
  const float* qp  = (const float*)d_in[13];
  const float* Wfp = (const float*)d_in[14];
  const float* bfp = (const float*)d_in[15];
  float* outp = (float*)d_out;

  const size_t R    = 65536;                     // B*T rows
  const size_t WB   = (size_t)NTOT * 512 * 2;    // bf16 weight block: 1,581,056 B
  const size_t QXB  = R * 8 * 4;                 // 2,097,152 B
  const size_t XP16 = R * NG * 2;                // 201,326,592 B
  const size_t XPF  = R * NTOT * 2;              // 202,375,168 B
  const size_t CNTB = (size_t)8 * 512 * 4;       // 16,384 B: flags[256] @0, xpub[256] @4096

  const size_t tA = XP16 + QXB + 3*WB;           // 208,166,912 B (r4-validated fit)
  const size_t tB = XPF + 2*WB;                  // 205,537,280 B

  char* ws = (char*)d_ws;

  if (ws_size >= tA){
    ushortT* xp     = (ushortT*)ws;
    float*   qx     = (float*)(ws + XP16);
    ushortT* btx    = (ushortT*)(ws + XP16 + QXB);
    ushortT* bth_hi = (ushortT*)(ws + XP16 + QXB + WB);
    ushortT* bth_lo = (ushortT*)(ws + XP16 + QXB + 2*WB);
    unsigned int* cnt = (unsigned int*)btx;      // btx dead after xproj
    prep_w<<<dim3(3088), dim3(256), 0, stream>>>(Wi, Wg, Wo, Wf, btx, bth_hi, bth_lo, 1);
    xproj_gemm<ushortT, true, NG><<<dim3(13, 512), dim3(256), 0, stream>>>(
        x, btx, bi, bg, bo, bfv, xp, qx);
    hipMemsetAsync(cnt, 0, CNTB, stream);        // stream-ordered: after xproj
    qlstm_rec<ushortT, true, true, NG><<<dim3(256), dim3(256), 0, stream>>>(
        outp, h0, c0, bth_hi, bth_lo, xp, qx, Wfp, bfp, qa, qb, qp, cnt);
  } else if (ws_size >= tB){
    ushortT* xp     = (ushortT*)ws;
    ushortT* btx    = (ushortT*)(ws + XPF);
    ushortT* bth_hi = (ushortT*)(ws + XPF + WB);
    unsigned int* cnt = (unsigned int*)btx;
    prep_w<<<dim3(3088), dim3(256), 0, stream>>>(Wi, Wg, Wo, Wf, btx, bth_hi, bth_hi, 0);
    xproj_gemm<ushortT, false, NTOT><<<dim3(13, 512), dim3(256), 0, stream>>>(
        x, btx, bi, bg, bo, bfv, xp, nullptr);
    hipMemsetAsync(cnt, 0, CNTB, stream);
    qlstm_rec<ushortT, false, false, NTOT><<<dim3(256), dim3(256), 0, stream>>>(
        outp, h0, c0, bth_hi, bth_hi, xp, nullptr, Wfp, bfp, qa, qb, qp, cnt);
  }
  // else: ws too small — leave out zeroed (fail loud with absmax = max|ref|)
}

// Round 3
// 5831.300 us; speedup vs baseline: 29.4663x; 29.4663x over previous
//
#include <hip/hip_runtime.h>
#include <stdint.h>

typedef unsigned short ushortT;
typedef unsigned long long u64T;
typedef __attribute__((ext_vector_type(8))) short short8;
typedef __attribute__((ext_vector_type(4))) float f32x4;

#define B_ 128
#define T_ 512
#define I_ 512
#define H_ 512
#define NG 1536     // 3*512 gate cols
#define NTOT 1544   // + 8 q cols

__device__ __forceinline__ float bf2f(ushortT u){
  union { unsigned int i; float f; } v; v.i = ((unsigned int)u) << 16; return v.f;
}
__device__ __forceinline__ ushortT f2bf(float f){           // RNE
  union { float f; unsigned int i; } v; v.f = f;
  unsigned int u = v.i;
  u += 0x7fffu + ((u >> 16) & 1u);
  return (ushortT)(u >> 16);
}
// truncating split: x == hi + lo to ~17 mantissa bits
__device__ __forceinline__ void splitf(float x, ushortT& hi, ushortT& lo){
  union { float f; unsigned int i; } v; v.f = x;
  hi = (ushortT)(v.i >> 16);
  union { unsigned int i; float f; } h; h.i = v.i & 0xffff0000u;
  union { float f; unsigned int i; } r; r.f = x - h.f;
  lo = (ushortT)(r.i >> 16);
}
__device__ __forceinline__ unsigned int packsplit(float x){
  ushortT hi, lo; splitf(x, hi, lo);
  return ((unsigned int)lo << 16) | (unsigned int)hi;
}
__device__ __forceinline__ float sigf(float x){ return 1.f / (1.f + __expf(-x)); }
__device__ __forceinline__ float tanhfast(float x){
  float e = __expf(-2.f * fabsf(x));
  float t = (1.f - e) / (1.f + e);
  return copysignf(t, x);
}
__device__ __forceinline__ void stx(float* p, size_t i, float v){ p[i] = v; }
__device__ __forceinline__ void stx(ushortT* p, size_t i, float v){ p[i] = f2bf(v); }
__device__ __forceinline__ float ldx(const float* p, size_t i){ return p[i]; }
__device__ __forceinline__ float ldx(const ushortT* p, size_t i){ return bf2f(p[i]); }
__device__ __forceinline__ unsigned int get_xcc(){
  unsigned int r;
  asm("s_getreg_b32 %0, hwreg(HW_REG_XCC_ID)" : "=s"(r));
  return r;
}

// ---------------------------------------------------------------------------
// Kernel A (validated r3/r4): weight prep. UNCHANGED.
// ---------------------------------------------------------------------------
__global__ __launch_bounds__(256) void prep_w(
    const float* __restrict__ Wi, const float* __restrict__ Wg,
    const float* __restrict__ Wo, const float* __restrict__ Wf,
    ushortT* __restrict__ btx, ushortT* __restrict__ bth_hi,
    ushortT* __restrict__ bth_lo, int wlo)
{
  int e = blockIdx.x * 256 + threadIdx.x;   // 1544*512 = 3088*256
  int n = e >> 9;
  int k = e & 511;
  const float* W; int ld, c;
  if (n < 512){ W = Wi; ld = 512; c = n; }
  else if (n < 1024){ W = Wg; ld = 512; c = n - 512; }
  else if (n < 1536){ W = Wo; ld = 512; c = n - 1024; }
  else { W = Wf; ld = 8; c = n - 1536; }
  btx[e] = f2bf(W[(size_t)k * ld + c]);
  float wh = W[(size_t)(512 + k) * ld + c];
  ushortT hi, lo; splitf(wh, hi, lo);
  bth_hi[e] = hi;
  if (wlo) bth_lo[e] = lo;
}

// ---------------------------------------------------------------------------
// Kernel B (validated r3/r4): xproj. UNCHANGED.
// ---------------------------------------------------------------------------
template<typename XPT, bool QX32, int XPST>
__global__ __launch_bounds__(256) void xproj_gemm(
    const float* __restrict__ x, const ushortT* __restrict__ btx,
    const float* __restrict__ bi, const float* __restrict__ bg,
    const float* __restrict__ bo, const float* __restrict__ bfv,
    XPT* __restrict__ xp, float* __restrict__ qx)
{
  __shared__ ushortT As[128][72];   // +8 pad
  __shared__ ushortT Bs[128][72];
  const int tid = threadIdx.x;
  const int n0 = blockIdx.x * 128;
  const int m0 = blockIdx.y * 128;
  const int wid = tid >> 6, lane = tid & 63;
  const int nn = lane & 15, quad = lane >> 4;

  f32x4 acc[2][8];
  #pragma unroll
  for (int a = 0; a < 2; ++a)
    #pragma unroll
    for (int b = 0; b < 8; ++b) acc[a][b] = (f32x4){0.f,0.f,0.f,0.f};

  for (int kb = 0; kb < 8; ++kb){
    #pragma unroll
    for (int u = 0; u < 4; ++u){
      int idx = u*256 + tid;
      int r = idx >> 3, k8 = (idx & 7) * 8;
      const float* xa = &x[(size_t)(m0 + r) * I_ + kb*64 + k8];
      f32x4 f0 = *(const f32x4*)xa;
      f32x4 f1 = *(const f32x4*)(xa + 4);
      short8 av;
      #pragma unroll
      for (int i = 0; i < 4; ++i){ av[i] = (short)f2bf(f0[i]); av[4+i] = (short)f2bf(f1[i]); }
      *(short8*)&As[r][k8] = av;
      int ng = n0 + r;
      short8 bv = {0,0,0,0,0,0,0,0};
      if (ng < NTOT)
        bv = *(const short8*)&btx[(size_t)ng * 512 + kb*64 + k8];
      *(short8*)&Bs[r][k8] = bv;
    }
    __syncthreads();
    #pragma unroll
    for (int kc = 0; kc < 2; ++kc){
      int ko = kc*32 + quad*8;
      short8 a0 = *(const short8*)&As[wid*32 + nn][ko];
      short8 a1 = *(const short8*)&As[wid*32 + 16 + nn][ko];
      #pragma unroll
      for (int nt = 0; nt < 8; ++nt){
        short8 b = *(const short8*)&Bs[nt*16 + nn][ko];
        acc[0][nt] = __builtin_amdgcn_mfma_f32_16x16x32_bf16(a0, b, acc[0][nt], 0,0,0);
        acc[1][nt] = __builtin_amdgcn_mfma_f32_16x16x32_bf16(a1, b, acc[1][nt], 0,0,0);
      }
    }
    __syncthreads();
  }
  #pragma unroll
  for (int nt = 0; nt < 8; ++nt){
    int c = n0 + nt*16 + nn;
    if (c >= NTOT) continue;
    float bias;
    if (c < 512) bias = bi[c];
    else if (c < 1024) bias = bg[c - 512];
    else if (c < NG) bias = bo[c - 1024];
    else bias = bfv[c - NG];
    #pragma unroll
    for (int mt = 0; mt < 2; ++mt){
      int rb = m0 + wid*32 + mt*16 + quad*4;
      #pragma unroll
      for (int r = 0; r < 4; ++r){
        float v = acc[mt][nt][r] + bias;
        if (c < NG)
          stx(xp, (size_t)(rb + r) * XPST + c, v);
        else if (QX32)
          qx[(size_t)(rb + r) * 8 + (c - NG)] = v;
        else
          stx(xp, (size_t)(rb + r) * XPST + c, v);
      }
    }
  }
}

// ---------------------------------------------------------------------------
// Kernel C: persistent recurrence. r7 — paired-group pipeline, r1-proven
// sync primitives ONLY.
//
// r2 post-mortem: hand-rolled sc0 poll loads did NOT bypass L1 on gfx950 ->
// stale flag reads -> 20M-iter timeouts (2.5s dispatches) + dead-block flag
// cascade. Fix: ALL flag traffic reverts to agent-scope atomics (MALL),
// exactly as the 2.65ms r1 kernel; flags are posted even after a timeout.
//
// Structure kept from r2 (the mechanism): 128 active blocks (even blk&7),
// block (p,s) owns col-slice s for groups 2p and 2p+1, sharing the 116KB
// LDS weight block. Serial phases A;B per step mean each phase's poll
// target was posted a full half-step earlier -> steady-state polls hit on
// the first read and each phase's jitter is absorbed by the other's
// compute. h exchange: plain stores/loads through the (handshake-verified)
// shared per-XCD L2 as in r1; agent-scope fallback otherwise.
// ---------------------------------------------------------------------------
template<typename XPT, bool QX32, bool WLO, int XPST>
__global__ __launch_bounds__(256) void qlstm_rec(
    float* __restrict__ dout, const float* __restrict__ h0,
    const float* __restrict__ c0,
    const ushortT* __restrict__ bth_hi, const ushortT* __restrict__ bth_lo,
    const XPT* __restrict__ xp, const float* __restrict__ qx,
    const float* __restrict__ Wfp, const float* __restrict__ bfp,
    const float* __restrict__ qa, const float* __restrict__ qbv,
    const float* __restrict__ qpar, unsigned int* __restrict__ cnt)
{
  __shared__ ushortT sWt[WLO ? 2 : 1][56][520];
  __shared__ unsigned int sH[16][516];   // packed (lo<<16)|hi per element
  __shared__ float sGb[3][16][16];
  __shared__ float sQbuf[16][8];
  __shared__ float sWfp[8][16];
  __shared__ float sBfp[16];
  __shared__ float sQa[3], sQn[3], sQp[8];
  __shared__ int sMode;

  const int xk = blockIdx.x & 7;
  if (xk & 1) return;                    // idle half exits (XCDs 1,3,5,7)
  const int tid = threadIdx.x;
  const int p = xk >> 1;                 // pair 0..3 -> groups 2p, 2p+1
  const int s = blockIdx.x >> 3;         // col slice 0..31
  const int j0 = s * 16;
  const int wid = tid >> 6, lane = tid & 63;
  const int nn = lane & 15, quad = lane >> 4;

  unsigned int* flg0 = cnt + ((p*2    ) << 5);   // flags[group][slice]
  unsigned int* flg1 = cnt + ((p*2 + 1) << 5);
  unsigned int* xpub = cnt + 1024;               // byte offset 4096

  // publish XCC id early so the handshake poll below rarely waits
  if (tid == 0)
    __hip_atomic_store(&xpub[blockIdx.x], (get_xcc() & 0xffu) | 0x100u,
                       __ATOMIC_RELAXED, __HIP_MEMORY_SCOPE_AGENT);

  // one-time LDS weight staging (rows: 16 Wi | 16 Wg | 16 Wo | 8 Wf)
  for (int u = tid; u < 56*64; u += 256){
    int r = u >> 6, c8 = (u & 63) * 8;
    int src = (r < 48) ? ((r >> 4) * 512 + j0 + (r & 15)) : (NG + (r - 48));
    *(short8*)&sWt[0][r][c8] = *(const short8*)&bth_hi[(size_t)src * 512 + c8];
    if (WLO)
      *(short8*)&sWt[WLO?1:0][r][c8] = *(const short8*)&bth_lo[(size_t)src * 512 + c8];
  }
  if (tid < 128){ int nq = tid >> 4, jj = tid & 15; sWfp[nq][jj] = Wfp[nq*512 + j0 + jj]; }
  if (tid < 16) sBfp[tid] = bfp[j0 + tid];
  if (tid < 3){ sQa[tid] = qa[tid]; sQn[tid] = qbv[tid]; }
  if (tid < 8) sQp[tid] = qpar[tid];

  // handshake: do all 32 blocks of this pair (blk = 2p + 8*s') share an XCD?
  if (wid == 0){
    int sl = lane & 31;
    unsigned int v = 0; long it = 0; bool timeout = false;
    for (;;){
      v = __hip_atomic_load(&xpub[(p << 1) + (sl << 3)], __ATOMIC_RELAXED,
                            __HIP_MEMORY_SCOPE_AGENT);
      if (__ballot(v != 0u) == ~0ull) break;
      __builtin_amdgcn_s_sleep(8);
      if (++it > 2000000L){ timeout = true; break; }
    }
    unsigned int v0 = __shfl(v, 0);
    bool same = (__ballot(v == v0) == ~0ull);
    if (tid == 0) sMode = (!timeout && same) ? 1 : 0;
  }

  const int eb = tid >> 4, ej = tid & 15;
  const int jg = j0 + ej;
  float cst[2];
  #pragma unroll
  for (int gi = 0; gi < 2; ++gi)
    cst[gi] = c0[(size_t)((p*2 + gi)*16 + eb) * H_ + jg];

  const int wrow = (wid < 3) ? (wid*16 + nn) : (48 + (nn & 7));
  const int ncol = (wid < 3) ? (wid*512 + j0 + nn) : (NG + nn);
  const bool colok = (wid < 3) || (nn < 8);

  // cooperative h-loader mapping: row = tid>>4, lane-interleaved columns
  const int lr = tid >> 4;
  const int lc0 = (tid & 15) * 2;          // u64 loads (agent path, t=0)
  const int lc4 = (tid & 15) * 4;          // uint4 loads (L2 path)
  const int lxs = (lr & 7) << 3;           // XOR swizzle (8-elem chunks)
  const int rxs = (nn & 7) << 3;
  bool dead = false;
  float hp1[2] = {0.f, 0.f}, hp2[2] = {0.f, 0.f};   // f32 h delay lines
  unsigned int* doutU = (unsigned int*)dout;

  __syncthreads();                         // staging + sMode ready
  const bool l2m = (sMode != 0);

  for (int t = 0; t < T_; ++t){
    #pragma unroll
    for (int gi = 0; gi < 2; ++gi){
      const int b0 = (p*2 + gi) * 16;
      unsigned int* flg = gi ? flg1 : flg0;

      // xp addends for this phase (issued before the poll -> HBM latency
      // overlaps flag detection)
      float xpv[4];
      #pragma unroll
      for (int r = 0; r < 4; ++r){
        int b = quad*4 + r;
        if (!colok){ xpv[r] = 0.f; continue; }
        if ((wid < 3) || !QX32)
          xpv[r] = ldx(xp, ((size_t)(b0 + b) * T_ + t) * XPST + ncol);
        else
          xpv[r] = qx[((size_t)(b0 + b) * T_ + t) * 8 + nn];
      }

      if (t > 0){
        if (wid == 0 && !dead){
          const unsigned int* fp = &flg[lane & 31];
          const unsigned int tgt = (unsigned int)t;
          bool ok = false; long it = 0;
          for (;;){
            if (!ok)
              ok = (__hip_atomic_load(fp, __ATOMIC_RELAXED,
                                      __HIP_MEMORY_SCOPE_AGENT) >= tgt);
            if (__ballot(ok) == ~0ull) break;
            __builtin_amdgcn_s_sleep(1);
            if (++it > 20000000L){ dead = true; break; }
          }
        }
        __syncthreads();
        const unsigned int* srow = doutU + ((size_t)(b0 + lr) * T_ + (t - 1)) * H_;
        if (l2m){
          // same-XCD: plain loads resolved in the shared L2 (t-unique addrs
          // -> consumer L1 can never hold a stale copy)  [r1-proven]
          #pragma unroll
          for (int i = 0; i < 8; ++i){
            int c = lc4 + i*64;
            *(uint4*)&sH[lr][c ^ lxs] = *(const uint4*)(srow + c);
          }
        } else {
          #pragma unroll
          for (int i = 0; i < 16; ++i){
            int c = lc0 + i*32;
            u64T v = __hip_atomic_load((const u64T*)(srow + c),
                                       __ATOMIC_RELAXED, __HIP_MEMORY_SCOPE_AGENT);
            *(u64T*)&sH[lr][c ^ lxs] = v;
          }
        }
        // flags>=t proves all peers consumed slice t-2 -> f32 rewrite safe
        if (t >= 2)
          dout[((size_t)(b0 + eb) * T_ + (t - 2)) * H_ + jg] = hp2[gi];
      } else {
        const float* srow = h0 + (size_t)(b0 + lr) * H_;
        #pragma unroll
        for (int i = 0; i < 16; ++i){
          int c = lc0 + i*32;
          u64T pk = (u64T)packsplit(srow[c]) | ((u64T)packsplit(srow[c + 1]) << 32);
          *(u64T*)&sH[lr][c ^ lxs] = pk;
        }
      }
      __syncthreads();

      f32x4 ac0 = {0.f,0.f,0.f,0.f}, ac1 = {0.f,0.f,0.f,0.f};
      #pragma unroll
      for (int kc = 0; kc < 16; ++kc){
        const unsigned int* hp = &sH[nn][(kc*32 + quad*8) ^ rxs];
        uint4 p0 = *(const uint4*)hp;
        uint4 p1 = *(const uint4*)(hp + 4);
        union { short8 sv; unsigned int u[4]; } Ah, Al;
        Ah.u[0] = __builtin_amdgcn_perm(p0.y, p0.x, 0x05040100u);
        Ah.u[1] = __builtin_amdgcn_perm(p0.w, p0.z, 0x05040100u);
        Ah.u[2] = __builtin_amdgcn_perm(p1.y, p1.x, 0x05040100u);
        Ah.u[3] = __builtin_amdgcn_perm(p1.w, p1.z, 0x05040100u);
        short8 bhi = *(const short8*)&sWt[0][wrow][kc*32 + quad*8];
        f32x4& acc = (kc & 1) ? ac1 : ac0;
        if (WLO){
          Al.u[0] = __builtin_amdgcn_perm(p0.y, p0.x, 0x07060302u);
          Al.u[1] = __builtin_amdgcn_perm(p0.w, p0.z, 0x07060302u);
          Al.u[2] = __builtin_amdgcn_perm(p1.y, p1.x, 0x07060302u);
          Al.u[3] = __builtin_amdgcn_perm(p1.w, p1.z, 0x07060302u);
          short8 blo = *(const short8*)&sWt[WLO?1:0][wrow][kc*32 + quad*8];
          acc = __builtin_amdgcn_mfma_f32_16x16x32_bf16(Al.sv, bhi, acc, 0,0,0);
          acc = __builtin_amdgcn_mfma_f32_16x16x32_bf16(Ah.sv, blo, acc, 0,0,0);
        }
        acc = __builtin_amdgcn_mfma_f32_16x16x32_bf16(Ah.sv, bhi, acc, 0,0,0);
      }
      f32x4 accv = ac0 + ac1;

      if (wid < 3){
        #pragma unroll
        for (int r = 0; r < 4; ++r){
          float v = accv[r] + xpv[r];
          v = (wid == 1) ? tanhfast(v) : sigf(v);
          sGb[wid][quad*4 + r][nn] = v;
        }
      } else if (nn < 8){
        float a0 = sQa[0], a1 = sQa[1], a2 = sQa[2];
        float n0v = sQn[0], n1 = sQn[1], n2 = sQn[2];
        float qp = sQp[nn];
        #pragma unroll
        for (int r = 0; r < 4; ++r){
          float v = accv[r] + xpv[r];
          v = tanhfast(v * a0 + n0v);
          v = tanhfast(v * a1 + n1);
          v = tanhfast(v * a2 + n2);
          sQbuf[quad*4 + r][nn] = v + qp;
        }
      }
      __syncthreads();

      float fpre = sBfp[ej];
      #pragma unroll
      for (int nq = 0; nq < 8; ++nq)
        fpre += sQbuf[eb][nq] * sWfp[nq][ej];
      float f = sigf(fpre);
      float iv = sGb[0][eb][ej], gv = sGb[1][eb][ej], ov = sGb[2][eb][ej];
      cst[gi] = f * cst[gi] + iv * gv;
      float hv = ov * tanhfast(cst[gi]);
      unsigned int pk = packsplit(hv);
      size_t oidx = ((size_t)(b0 + eb) * T_ + t) * H_ + jg;
      if (l2m)
        doutU[oidx] = pk;                           // plain store, L2-resolved
      else
        __hip_atomic_store(&doutU[oidx], pk, __ATOMIC_RELAXED,
                           __HIP_MEMORY_SCOPE_AGENT);
      hp2[gi] = hp1[gi]; hp1[gi] = hv;

      __syncthreads();   // s_waitcnt vmcnt(0) before s_barrier: h committed
      // Post even if dead: prevents the r2 timeout cascade (peers keep
      // making progress; a truly broken run fails loud via absmax).
      if (tid == 0)
        __hip_atomic_store(&flg[s], (unsigned int)(t + 1), __ATOMIC_RELAXED,
                           __HIP_MEMORY_SCOPE_AGENT);
    }
  }

  // Final slice fixup: slice T-2 may still be read by stragglers at their
  // step T-1 -> wait for every flag of the group to reach T first.
  #pragma unroll
  for (int gi = 0; gi < 2; ++gi){
    unsigned int* flg = gi ? flg1 : flg0;
    if (wid == 0 && !dead){
      const unsigned int* fp = &flg[lane & 31];
      bool ok = false; long it = 0;
      for (;;){
        if (!ok)
          ok = (__hip_atomic_load(fp, __ATOMIC_RELAXED,
                                  __HIP_MEMORY_SCOPE_AGENT) >= (unsigned int)T_);
        if (__ballot(ok) == ~0ull) break;
        __builtin_amdgcn_s_sleep(1);
        if (++it > 20000000L) break;
      }
    }
    __syncthreads();
    const int b0 = (p*2 + gi) * 16;
    dout[((size_t)(b0 + eb) * T_ + (T_ - 2)) * H_ + jg] = hp2[gi];
    dout[((size_t)(b0 + eb) * T_ + (T_ - 1)) * H_ + jg] = hp1[gi];
  }
}

// ---------------------------------------------------------------------------
extern "C" void kernel_launch(void* const* d_in, const int* in_sizes, int n_in,
                              void* d_out, int out_size, void* d_ws, size_t ws_size,
                              hipStream_t stream)
{
  const float* x   = (const float*)d_in[0];
  const float* h0  = (const float*)d_in[1];
  const float* c0  = (const float*)d_in[2];
  const float* Wi  = (const float*)d_in[3];
  const float* bi  = (const float*)d_in[4];
  const float* Wg  = (const float*)d_in[5];
  const float* bg  = (const float*)d_in[6];
  const float* Wo  = (const float*)d_in[7];
  const float* bo  = (const float*)d_in[8];
  const float* Wf  = (const float*)d_in[9];
  const float* bfv = (const float*)d_in[10];
  const float* qa  = (const float*)d_in[11];
  const float* qb  = (const float*)d_in[12];
  const float* qp  = (const float*)d_in[13];
  const float* Wfp = (const float*)d_in[14];
  const float* bfp = (const float*)d_in[15];
  float* outp = (float*)d_out;

  const size_t R    = 65536;                     // B*T rows
  const size_t WB   = (size_t)NTOT * 512 * 2;    // bf16 weight block: 1,581,056 B
  const size_t QXB  = R * 8 * 4;                 // 2,097,152 B
  const size_t XP16 = R * NG * 2;                // 201,326,592 B
  const size_t XPF  = R * NTOT * 2;              // 202,375,168 B
  const size_t CNTB = (size_t)8 * 512 * 4;       // 16,384 B: flags[256] @0, xpub[256] @4096

  const size_t tA = XP16 + QXB + 3*WB;           // 208,166,912 B (r4-validated fit)
  const size_t tB = XPF + 2*WB;                  // 205,537,280 B

  char* ws = (char*)d_ws;

  if (ws_size >= tA){
    ushortT* xp     = (ushortT*)ws;
    float*   qx     = (float*)(ws + XP16);
    ushortT* btx    = (ushortT*)(ws + XP16 + QXB);
    ushortT* bth_hi = (ushortT*)(ws + XP16 + QXB + WB);
    ushortT* bth_lo = (ushortT*)(ws + XP16 + QXB + 2*WB);
    unsigned int* cnt = (unsigned int*)btx;      // btx dead after xproj
    prep_w<<<dim3(3088), dim3(256), 0, stream>>>(Wi, Wg, Wo, Wf, btx, bth_hi, bth_lo, 1);
    xproj_gemm<ushortT, true, NG><<<dim3(13, 512), dim3(256), 0, stream>>>(
        x, btx, bi, bg, bo, bfv, xp, qx);
    hipMemsetAsync(cnt, 0, CNTB, stream);        // stream-ordered: after xproj
    qlstm_rec<ushortT, true, true, NG><<<dim3(256), dim3(256), 0, stream>>>(
        outp, h0, c0, bth_hi, bth_lo, xp, qx, Wfp, bfp, qa, qb, qp, cnt);
  } else if (ws_size >= tB){
    ushortT* xp     = (ushortT*)ws;
    ushortT* btx    = (ushortT*)(ws + XPF);
    ushortT* bth_hi = (ushortT*)(ws + XPF + WB);
    unsigned int* cnt = (unsigned int*)btx;
    prep_w<<<dim3(3088), dim3(256), 0, stream>>>(Wi, Wg, Wo, Wf, btx, bth_hi, bth_hi, 0);
    xproj_gemm<ushortT, false, NTOT><<<dim3(13, 512), dim3(256), 0, stream>>>(
        x, btx, bi, bg, bo, bfv, xp, nullptr);
    hipMemsetAsync(cnt, 0, CNTB, stream);
    qlstm_rec<ushortT, false, false, NTOT><<<dim3(256), dim3(256), 0, stream>>>(
        outp, h0, c0, bth_hi, bth_hi, xp, nullptr, Wfp, bfp, qa, qb, qp, cnt);
  }
  // else: ws too small — leave out zeroed (fail loud with absmax = max|ref|)
}

// Round 4
// 3024.002 us; speedup vs baseline: 56.8210x; 1.9283x over previous
//
#include <hip/hip_runtime.h>
#include <stdint.h>

typedef unsigned short ushortT;
typedef unsigned long long u64T;
typedef __attribute__((ext_vector_type(8))) short short8;
typedef __attribute__((ext_vector_type(4))) float f32x4;

#define B_ 128
#define T_ 512
#define I_ 512
#define H_ 512
#define NG 1536     // 3*512 gate cols
#define NTOT 1544   // + 8 q cols

__device__ __forceinline__ float bf2f(ushortT u){
  union { unsigned int i; float f; } v; v.i = ((unsigned int)u) << 16; return v.f;
}
__device__ __forceinline__ ushortT f2bf(float f){           // RNE
  union { float f; unsigned int i; } v; v.f = f;
  unsigned int u = v.i;
  u += 0x7fffu + ((u >> 16) & 1u);
  return (ushortT)(u >> 16);
}
// truncating split: x == hi + lo to ~17 mantissa bits
__device__ __forceinline__ void splitf(float x, ushortT& hi, ushortT& lo){
  union { float f; unsigned int i; } v; v.f = x;
  hi = (ushortT)(v.i >> 16);
  union { unsigned int i; float f; } h; h.i = v.i & 0xffff0000u;
  union { float f; unsigned int i; } r; r.f = x - h.f;
  lo = (ushortT)(r.i >> 16);
}
__device__ __forceinline__ unsigned int packsplit(float x){
  ushortT hi, lo; splitf(x, hi, lo);
  return ((unsigned int)lo << 16) | (unsigned int)hi;
}
__device__ __forceinline__ float sigf(float x){ return 1.f / (1.f + __expf(-x)); }
__device__ __forceinline__ float tanhfast(float x){
  float e = __expf(-2.f * fabsf(x));
  float t = (1.f - e) / (1.f + e);
  return copysignf(t, x);
}
__device__ __forceinline__ void stx(float* p, size_t i, float v){ p[i] = v; }
__device__ __forceinline__ void stx(ushortT* p, size_t i, float v){ p[i] = f2bf(v); }
__device__ __forceinline__ float ldx(const float* p, size_t i){ return p[i]; }
__device__ __forceinline__ float ldx(const ushortT* p, size_t i){ return bf2f(p[i]); }
__device__ __forceinline__ unsigned int get_xcc(){
  unsigned int r;
  asm("s_getreg_b32 %0, hwreg(HW_REG_XCC_ID)" : "=s"(r));
  return r;
}

// ---------------------------------------------------------------------------
// Kernel A (validated r3/r4): weight prep. UNCHANGED.
// ---------------------------------------------------------------------------
__global__ __launch_bounds__(256) void prep_w(
    const float* __restrict__ Wi, const float* __restrict__ Wg,
    const float* __restrict__ Wo, const float* __restrict__ Wf,
    ushortT* __restrict__ btx, ushortT* __restrict__ bth_hi,
    ushortT* __restrict__ bth_lo, int wlo)
{
  int e = blockIdx.x * 256 + threadIdx.x;   // 1544*512 = 3088*256
  int n = e >> 9;
  int k = e & 511;
  const float* W; int ld, c;
  if (n < 512){ W = Wi; ld = 512; c = n; }
  else if (n < 1024){ W = Wg; ld = 512; c = n - 512; }
  else if (n < 1536){ W = Wo; ld = 512; c = n - 1024; }
  else { W = Wf; ld = 8; c = n - 1536; }
  btx[e] = f2bf(W[(size_t)k * ld + c]);
  float wh = W[(size_t)(512 + k) * ld + c];
  ushortT hi, lo; splitf(wh, hi, lo);
  bth_hi[e] = hi;
  if (wlo) bth_lo[e] = lo;
}

// ---------------------------------------------------------------------------
// Kernel B (validated r3/r4): xproj. UNCHANGED.
// ---------------------------------------------------------------------------
template<typename XPT, bool QX32, int XPST>
__global__ __launch_bounds__(256) void xproj_gemm(
    const float* __restrict__ x, const ushortT* __restrict__ btx,
    const float* __restrict__ bi, const float* __restrict__ bg,
    const float* __restrict__ bo, const float* __restrict__ bfv,
    XPT* __restrict__ xp, float* __restrict__ qx)
{
  __shared__ ushortT As[128][72];   // +8 pad
  __shared__ ushortT Bs[128][72];
  const int tid = threadIdx.x;
  const int n0 = blockIdx.x * 128;
  const int m0 = blockIdx.y * 128;
  const int wid = tid >> 6, lane = tid & 63;
  const int nn = lane & 15, quad = lane >> 4;

  f32x4 acc[2][8];
  #pragma unroll
  for (int a = 0; a < 2; ++a)
    #pragma unroll
    for (int b = 0; b < 8; ++b) acc[a][b] = (f32x4){0.f,0.f,0.f,0.f};

  for (int kb = 0; kb < 8; ++kb){
    #pragma unroll
    for (int u = 0; u < 4; ++u){
      int idx = u*256 + tid;
      int r = idx >> 3, k8 = (idx & 7) * 8;
      const float* xa = &x[(size_t)(m0 + r) * I_ + kb*64 + k8];
      f32x4 f0 = *(const f32x4*)xa;
      f32x4 f1 = *(const f32x4*)(xa + 4);
      short8 av;
      #pragma unroll
      for (int i = 0; i < 4; ++i){ av[i] = (short)f2bf(f0[i]); av[4+i] = (short)f2bf(f1[i]); }
      *(short8*)&As[r][k8] = av;
      int ng = n0 + r;
      short8 bv = {0,0,0,0,0,0,0,0};
      if (ng < NTOT)
        bv = *(const short8*)&btx[(size_t)ng * 512 + kb*64 + k8];
      *(short8*)&Bs[r][k8] = bv;
    }
    __syncthreads();
    #pragma unroll
    for (int kc = 0; kc < 2; ++kc){
      int ko = kc*32 + quad*8;
      short8 a0 = *(const short8*)&As[wid*32 + nn][ko];
      short8 a1 = *(const short8*)&As[wid*32 + 16 + nn][ko];
      #pragma unroll
      for (int nt = 0; nt < 8; ++nt){
        short8 b = *(const short8*)&Bs[nt*16 + nn][ko];
        acc[0][nt] = __builtin_amdgcn_mfma_f32_16x16x32_bf16(a0, b, acc[0][nt], 0,0,0);
        acc[1][nt] = __builtin_amdgcn_mfma_f32_16x16x32_bf16(a1, b, acc[1][nt], 0,0,0);
      }
    }
    __syncthreads();
  }
  #pragma unroll
  for (int nt = 0; nt < 8; ++nt){
    int c = n0 + nt*16 + nn;
    if (c >= NTOT) continue;
    float bias;
    if (c < 512) bias = bi[c];
    else if (c < 1024) bias = bg[c - 512];
    else if (c < NG) bias = bo[c - 1024];
    else bias = bfv[c - NG];
    #pragma unroll
    for (int mt = 0; mt < 2; ++mt){
      int rb = m0 + wid*32 + mt*16 + quad*4;
      #pragma unroll
      for (int r = 0; r < 4; ++r){
        float v = acc[mt][nt][r] + bias;
        if (c < NG)
          stx(xp, (size_t)(rb + r) * XPST + c, v);
        else if (QX32)
          qx[(size_t)(rb + r) * 8 + (c - NG)] = v;
        else
          stx(xp, (size_t)(rb + r) * XPST + c, v);
      }
    }
  }
}

// ---------------------------------------------------------------------------
// Kernel C: persistent recurrence. r8 — r1 structure (2646us proven: 256
// blocks, 1 group/block, agent-scope flags) + intra-phase critical-path cuts.
//
// r3 falsified the straggler-slack theory (paired phases with a half-step of
// posted slack ran at exactly r1's per-phase time) => the 12.4k-cycle step is
// the serial intra-phase path at 1 wave/SIMD. Cuts:
//  (1) WEIGHTS IN VGPRs: occupancy is pinned at 1 block/CU, so 128 VGPRs of
//      time-invariant weight fragments are free. Deletes sWt (LDS 154->37KB),
//      halves MFMA-loop LDS traffic (64->32 ds_read_b128 per lane-step) and
//      removes the sWt bank-clash (row stride 260 words => ~8-way).
//  (2) t-2 f32 rewrite issued AFTER the post-load barrier: its HBM store-ack
//      drains ~2k cycles later at the gates barrier, not immediately.
//  (3) all-wave flag poll (each wave ballots the 32 flags) removes the
//      poll->barrier edge. Flags stay agent-scope atomics (r2 lesson).
// ---------------------------------------------------------------------------
template<typename XPT, bool QX32, bool WLO, int XPST>
__global__ __launch_bounds__(256, 1) void qlstm_rec(
    float* __restrict__ dout, const float* __restrict__ h0,
    const float* __restrict__ c0,
    const ushortT* __restrict__ bth_hi, const ushortT* __restrict__ bth_lo,
    const XPT* __restrict__ xp, const float* __restrict__ qx,
    const float* __restrict__ Wfp, const float* __restrict__ bfp,
    const float* __restrict__ qa, const float* __restrict__ qbv,
    const float* __restrict__ qpar, unsigned int* __restrict__ cnt)
{
  __shared__ unsigned int sH[16][516];   // packed (lo<<16)|hi per element
  __shared__ float sGb[3][16][16];
  __shared__ float sQbuf[16][8];
  __shared__ float sWfp[8][16];
  __shared__ float sBfp[16];
  __shared__ float sQa[3], sQn[3], sQp[8];
  __shared__ int sMode;

  const int tid = threadIdx.x;
  const int g = blockIdx.x & 7, s = blockIdx.x >> 3;
  const int b0 = g * 16, j0 = s * 16;
  const int wid = tid >> 6, lane = tid & 63;
  const int nn = lane & 15, quad = lane >> 4;

  unsigned int* flagsG = cnt + (g << 5);         // flags[group][slice]
  unsigned int* xpub   = cnt + 1024;             // byte offset 4096

  // publish XCC id early so the handshake poll below rarely waits
  if (tid == 0)
    __hip_atomic_store(&xpub[blockIdx.x], (get_xcc() & 0xffu) | 0x100u,
                       __ATOMIC_RELAXED, __HIP_MEMORY_SCOPE_AGENT);

  // one-time weight staging straight into REGISTERS (time-invariant).
  // Fragment for lane (nn,quad) of wave wid: weight col wsrc, k-span
  // kc*32+quad*8. (For wid==3, nn>=8 lanes duplicate nn&7 — harmless.)
  const int wsrc = (wid < 3) ? (wid*512 + j0 + nn) : (NG + (nn & 7));
  short8 whi[16], wlo_[16];
  #pragma unroll
  for (int kc = 0; kc < 16; ++kc){
    whi[kc] = *(const short8*)&bth_hi[(size_t)wsrc * 512 + kc*32 + quad*8];
    if (WLO)
      wlo_[kc] = *(const short8*)&bth_lo[(size_t)wsrc * 512 + kc*32 + quad*8];
  }
  if (tid < 128){ int nq = tid >> 4, jj = tid & 15; sWfp[nq][jj] = Wfp[nq*512 + j0 + jj]; }
  if (tid < 16) sBfp[tid] = bfp[j0 + tid];
  if (tid < 3){ sQa[tid] = qa[tid]; sQn[tid] = qbv[tid]; }
  if (tid < 8) sQp[tid] = qpar[tid];

  // handshake: do all 32 blocks of this group share an XCD?
  if (wid == 0){
    int sl = lane & 31;
    unsigned int v = 0; long it = 0; bool timeout = false;
    for (;;){
      v = __hip_atomic_load(&xpub[g + (sl << 3)], __ATOMIC_RELAXED,
                            __HIP_MEMORY_SCOPE_AGENT);
      if (__ballot(v != 0u) == ~0ull) break;
      __builtin_amdgcn_s_sleep(8);
      if (++it > 2000000L){ timeout = true; break; }
    }
    unsigned int v0 = __shfl(v, 0);
    bool same = (__ballot(v == v0) == ~0ull);
    if (tid == 0) sMode = (!timeout && same) ? 1 : 0;
  }

  const int eb = tid >> 4, ej = tid & 15;
  const int jg = j0 + ej;
  float cst = c0[(size_t)(b0 + eb) * H_ + jg];

  const int ncol = (wid < 3) ? (wid*512 + j0 + nn) : (NG + nn);
  const bool colok = (wid < 3) || (nn < 8);

  // cooperative h-loader mapping: row = tid>>4, lane-interleaved columns
  const int lr = tid >> 4;
  const int lc0 = (tid & 15) * 2;          // u64 loads (agent path, t=0)
  const int lc4 = (tid & 15) * 4;          // uint4 loads (L2 path)
  const int lxs = (lr & 7) << 3;           // XOR swizzle (8-elem chunks)
  const int rxs = (nn & 7) << 3;
  bool dead = false;
  float hp1 = 0.f, hp2 = 0.f;              // f32 h delay line for dout fixup
  unsigned int* doutU = (unsigned int*)dout;

  __syncthreads();                         // staging + sMode ready
  const bool l2m = (sMode != 0);

  for (int t = 0; t < T_; ++t){
    // xp addends (t-unique HBM loads; issued before the poll so their
    // latency overlaps flag detection)
    float xpv[4];
    #pragma unroll
    for (int r = 0; r < 4; ++r){
      int b = quad*4 + r;
      if (!colok){ xpv[r] = 0.f; continue; }
      if ((wid < 3) || !QX32)
        xpv[r] = ldx(xp, ((size_t)(b0 + b) * T_ + t) * XPST + ncol);
      else
        xpv[r] = qx[((size_t)(b0 + b) * T_ + t) * 8 + nn];
    }

    if (t > 0){
      // all-wave poll: every wave verifies all 32 flags itself (2 lanes per
      // flag), so no barrier is needed before the per-wave sH row loads.
      if (!dead){
        const unsigned int* fp = &flagsG[lane & 31];
        const unsigned int tgt = (unsigned int)t;
        bool ok = false; long it = 0;
        for (;;){
          if (!ok)
            ok = (__hip_atomic_load(fp, __ATOMIC_RELAXED,
                                    __HIP_MEMORY_SCOPE_AGENT) >= tgt);
          if (__ballot(ok) == ~0ull) break;
          __builtin_amdgcn_s_sleep(1);
          if (++it > 20000000L){ dead = true; break; }
        }
      }
      const unsigned int* srow = doutU + ((size_t)(b0 + lr) * T_ + (t - 1)) * H_;
      if (l2m){
        // same-XCD: plain loads resolved in the shared L2 (t-unique addrs
        // -> consumer L1 can never hold a stale copy)  [r1-proven]
        #pragma unroll
        for (int i = 0; i < 8; ++i){
          int c = lc4 + i*64;
          *(uint4*)&sH[lr][c ^ lxs] = *(const uint4*)(srow + c);
        }
      } else {
        #pragma unroll
        for (int i = 0; i < 16; ++i){
          int c = lc0 + i*32;
          u64T v = __hip_atomic_load((const u64T*)(srow + c),
                                     __ATOMIC_RELAXED, __HIP_MEMORY_SCOPE_AGENT);
          *(u64T*)&sH[lr][c ^ lxs] = v;
        }
      }
    } else {
      const float* srow = h0 + (size_t)(b0 + lr) * H_;
      #pragma unroll
      for (int i = 0; i < 16; ++i){
        int c = lc0 + i*32;
        u64T pk = (u64T)packsplit(srow[c]) | ((u64T)packsplit(srow[c + 1]) << 32);
        *(u64T*)&sH[lr][c ^ lxs] = pk;
      }
    }
    __syncthreads();

    // t-2 f32 rewrite AFTER the barrier: flags>=t (established by this
    // wave's own poll) proves all peers consumed slice t-2. Issued here so
    // its HBM store-ack drains at the gates barrier, hidden under the MFMA
    // loop instead of at the barrier right above.
    if (t >= 2)
      dout[((size_t)(b0 + eb) * T_ + (t - 2)) * H_ + jg] = hp2;

    f32x4 ac0 = {0.f,0.f,0.f,0.f}, ac1 = {0.f,0.f,0.f,0.f};
    #pragma unroll
    for (int kc = 0; kc < 16; ++kc){
      const unsigned int* hp = &sH[nn][(kc*32 + quad*8) ^ rxs];
      uint4 p0 = *(const uint4*)hp;
      uint4 p1 = *(const uint4*)(hp + 4);
      union { short8 sv; unsigned int u[4]; } Ah, Al;
      Ah.u[0] = __builtin_amdgcn_perm(p0.y, p0.x, 0x05040100u);
      Ah.u[1] = __builtin_amdgcn_perm(p0.w, p0.z, 0x05040100u);
      Ah.u[2] = __builtin_amdgcn_perm(p1.y, p1.x, 0x05040100u);
      Ah.u[3] = __builtin_amdgcn_perm(p1.w, p1.z, 0x05040100u);
      f32x4& acc = (kc & 1) ? ac1 : ac0;
      if (WLO){
        Al.u[0] = __builtin_amdgcn_perm(p0.y, p0.x, 0x07060302u);
        Al.u[1] = __builtin_amdgcn_perm(p0.w, p0.z, 0x07060302u);
        Al.u[2] = __builtin_amdgcn_perm(p1.y, p1.x, 0x07060302u);
        Al.u[3] = __builtin_amdgcn_perm(p1.w, p1.z, 0x07060302u);
        acc = __builtin_amdgcn_mfma_f32_16x16x32_bf16(Al.sv, whi[kc], acc, 0,0,0);
        acc = __builtin_amdgcn_mfma_f32_16x16x32_bf16(Ah.sv, wlo_[kc], acc, 0,0,0);
      }
      acc = __builtin_amdgcn_mfma_f32_16x16x32_bf16(Ah.sv, whi[kc], acc, 0,0,0);
    }
    f32x4 accv = ac0 + ac1;

    if (wid < 3){
      #pragma unroll
      for (int r = 0; r < 4; ++r){
        float v = accv[r] + xpv[r];
        v = (wid == 1) ? tanhfast(v) : sigf(v);
        sGb[wid][quad*4 + r][nn] = v;
      }
    } else if (nn < 8){
      float a0 = sQa[0], a1 = sQa[1], a2 = sQa[2];
      float n0v = sQn[0], n1 = sQn[1], n2 = sQn[2];
      float qp = sQp[nn];
      #pragma unroll
      for (int r = 0; r < 4; ++r){
        float v = accv[r] + xpv[r];
        v = tanhfast(v * a0 + n0v);
        v = tanhfast(v * a1 + n1);
        v = tanhfast(v * a2 + n2);
        sQbuf[quad*4 + r][nn] = v + qp;
      }
    }
    __syncthreads();

    float fpre = sBfp[ej];
    #pragma unroll
    for (int nq = 0; nq < 8; ++nq)
      fpre += sQbuf[eb][nq] * sWfp[nq][ej];
    float f = sigf(fpre);
    float iv = sGb[0][eb][ej], gv = sGb[1][eb][ej], ov = sGb[2][eb][ej];
    cst = f * cst + iv * gv;
    float hv = ov * tanhfast(cst);
    unsigned int pk = packsplit(hv);
    size_t oidx = ((size_t)(b0 + eb) * T_ + t) * H_ + jg;
    if (l2m)
      doutU[oidx] = pk;                           // plain store, L2-resolved
    else
      __hip_atomic_store(&doutU[oidx], pk, __ATOMIC_RELAXED,
                         __HIP_MEMORY_SCOPE_AGENT);
    hp2 = hp1; hp1 = hv;

    __syncthreads();   // s_waitcnt vmcnt(0) before s_barrier: h committed
    // Post even if dead: prevents timeout cascade (r2 lesson); a truly
    // broken run fails loud via absmax.
    if (tid == 0)
      __hip_atomic_store(&flagsG[s], (unsigned int)(t + 1), __ATOMIC_RELAXED,
                         __HIP_MEMORY_SCOPE_AGENT);
  }

  // Final slice fixup: slice T-2 may still be read by stragglers at their
  // step T-1 -> wait for every flag to reach T before overwriting.
  if (wid == 0 && !dead){
    const unsigned int* fp = &flagsG[lane & 31];
    bool ok = false; long it = 0;
    for (;;){
      if (!ok)
        ok = (__hip_atomic_load(fp, __ATOMIC_RELAXED,
                                __HIP_MEMORY_SCOPE_AGENT) >= (unsigned int)T_);
      if (__ballot(ok) == ~0ull) break;
      __builtin_amdgcn_s_sleep(1);
      if (++it > 20000000L) break;
    }
  }
  __syncthreads();
  dout[((size_t)(b0 + eb) * T_ + (T_ - 2)) * H_ + jg] = hp2;
  dout[((size_t)(b0 + eb) * T_ + (T_ - 1)) * H_ + jg] = hp1;
}

// ---------------------------------------------------------------------------
extern "C" void kernel_launch(void* const* d_in, const int* in_sizes, int n_in,
                              void* d_out, int out_size, void* d_ws, size_t ws_size,
                              hipStream_t stream)
{
  const float* x   = (const float*)d_in[0];
  const float* h0  = (const float*)d_in[1];
  const float* c0  = (const float*)d_in[2];
  const float* Wi  = (const float*)d_in[3];
  const float* bi  = (const float*)d_in[4];
  const float* Wg  = (const float*)d_in[5];
  const float* bg  = (const float*)d_in[6];
  const float* Wo  = (const float*)d_in[7];
  const float* bo  = (const float*)d_in[8];
  const float* Wf  = (const float*)d_in[9];
  const float* bfv = (const float*)d_in[10];
  const float* qa  = (const float*)d_in[11];
  const float* qb  = (const float*)d_in[12];
  const float* qp  = (const float*)d_in[13];
  const float* Wfp = (const float*)d_in[14];
  const float* bfp = (const float*)d_in[15];
  float* outp = (float*)d_out;

  const size_t R    = 65536;                     // B*T rows
  const size_t WB   = (size_t)NTOT * 512 * 2;    // bf16 weight block: 1,581,056 B
  const size_t QXB  = R * 8 * 4;                 // 2,097,152 B
  const size_t XP16 = R * NG * 2;                // 201,326,592 B
  const size_t XPF  = R * NTOT * 2;              // 202,375,168 B
  const size_t CNTB = (size_t)8 * 512 * 4;       // 16,384 B: flags[256] @0, xpub[256] @4096

  const size_t tA = XP16 + QXB + 3*WB;           // 208,166,912 B (r4-validated fit)
  const size_t tB = XPF + 2*WB;                  // 205,537,280 B

  char* ws = (char*)d_ws;

  if (ws_size >= tA){
    ushortT* xp     = (ushortT*)ws;
    float*   qx     = (float*)(ws + XP16);
    ushortT* btx    = (ushortT*)(ws + XP16 + QXB);
    ushortT* bth_hi = (ushortT*)(ws + XP16 + QXB + WB);
    ushortT* bth_lo = (ushortT*)(ws + XP16 + QXB + 2*WB);
    unsigned int* cnt = (unsigned int*)btx;      // btx dead after xproj
    prep_w<<<dim3(3088), dim3(256), 0, stream>>>(Wi, Wg, Wo, Wf, btx, bth_hi, bth_lo, 1);
    xproj_gemm<ushortT, true, NG><<<dim3(13, 512), dim3(256), 0, stream>>>(
        x, btx, bi, bg, bo, bfv, xp, qx);
    hipMemsetAsync(cnt, 0, CNTB, stream);        // stream-ordered: after xproj
    qlstm_rec<ushortT, true, true, NG><<<dim3(256), dim3(256), 0, stream>>>(
        outp, h0, c0, bth_hi, bth_lo, xp, qx, Wfp, bfp, qa, qb, qp, cnt);
  } else if (ws_size >= tB){
    ushortT* xp     = (ushortT*)ws;
    ushortT* btx    = (ushortT*)(ws + XPF);
    ushortT* bth_hi = (ushortT*)(ws + XPF + WB);
    unsigned int* cnt = (unsigned int*)btx;
    prep_w<<<dim3(3088), dim3(256), 0, stream>>>(Wi, Wg, Wo, Wf, btx, bth_hi, bth_hi, 0);
    xproj_gemm<ushortT, false, NTOT><<<dim3(13, 512), dim3(256), 0, stream>>>(
        x, btx, bi, bg, bo, bfv, xp, nullptr);
    hipMemsetAsync(cnt, 0, CNTB, stream);
    qlstm_rec<ushortT, false, false, NTOT><<<dim3(256), dim3(256), 0, stream>>>(
        outp, h0, c0, bth_hi, bth_hi, xp, nullptr, Wfp, bfp, qa, qb, qp, cnt);
  }
  // else: ws too small — leave out zeroed (fail loud with absmax = max|ref|)
}